// Round 13
// baseline (324.898 us; speedup 1.0000x reference)
//
#include <hip/hip_runtime.h>
#include <hip/hip_bf16.h>

// Problem constants (fixed by the reference)
#define NN 50000
#define FIN 128
#define NH 2
#define C1 64
#define C2 32
#define NE 800000
#define NEG 0.2f

typedef unsigned int uint32;

__device__ __forceinline__ float lrelu(float v) { return v > 0.0f ? v : NEG * v; }
__device__ __forceinline__ float dot4(float4 a, float4 b) {
    return a.x * b.x + a.y * b.y + a.z * b.z + a.w * b.w;
}
// pack two f32 -> bf16x2 (round-to-nearest-even; inputs finite)
__device__ __forceinline__ uint32 packbf2(float a, float b) {
    uint32 ua = __float_as_uint(a), ub = __float_as_uint(b);
    ua += 0x7fffu + ((ua >> 16) & 1u);
    ub += 0x7fffu + ((ub >> 16) & 1u);
    return (ua >> 16) | (ub & 0xffff0000u);
}
__device__ __forceinline__ float bfsel(uint32 u, int odd) {
    return __uint_as_float(odd ? (u & 0xffff0000u) : (u << 16));
}
// async 16B global -> LDS DMA. LDS dest: wave-uniform base + lane*16 (m104).
__device__ __forceinline__ void gload16(const float* g, float* l) {
    __builtin_amdgcn_global_load_lds(
        (const __attribute__((address_space(1))) unsigned int*)g,
        (__attribute__((address_space(3))) unsigned int*)l, 16, 0, 0);
}

// ---------------- CSR build ----------------
__global__ void zero_ints(int* __restrict__ a, int n) {
    for (int i = blockIdx.x * blockDim.x + threadIdx.x; i < n;
         i += gridDim.x * blockDim.x) a[i] = 0;
}

__global__ void hist_dst(const int* __restrict__ ei, int* __restrict__ deg) {
    const int i = blockIdx.x * blockDim.x + threadIdx.x;
    if (i >= NE) return;
    atomicAdd(&deg[ei[NE + i]], 1);
}

__global__ void scan_blocks(const int* __restrict__ deg, int* __restrict__ offs,
                            int* __restrict__ bsum) {
    __shared__ int sm[256];
    const int t = threadIdx.x;
    const int i = blockIdx.x * 256 + t;
    const int v = (i < NN) ? deg[i] : 0;
    sm[t] = v;
    __syncthreads();
    int x = v;
    #pragma unroll
    for (int d = 1; d < 256; d <<= 1) {
        const int y = (t >= d) ? sm[t - d] : 0;
        __syncthreads();
        x += y; sm[t] = x;
        __syncthreads();
    }
    if (i < NN) offs[i] = x - v;
    if (t == 255) bsum[blockIdx.x] = x;
}

__global__ void scan_bsums(int* __restrict__ bsum, int nb) {
    __shared__ int sm[256];
    const int t = threadIdx.x;
    const int v = (t < nb) ? bsum[t] : 0;
    sm[t] = v;
    __syncthreads();
    int x = v;
    #pragma unroll
    for (int d = 1; d < 256; d <<= 1) {
        const int y = (t >= d) ? sm[t - d] : 0;
        __syncthreads();
        x += y; sm[t] = x;
        __syncthreads();
    }
    if (t < nb) bsum[t] = x - v;
}

__global__ void scan_add(int* __restrict__ offs, const int* __restrict__ bsum) {
    const int i = blockIdx.x * 256 + threadIdx.x;
    if (i < NN) offs[i] += bsum[blockIdx.x];
}

__global__ void csr_scatter(const int* __restrict__ ei, const int* __restrict__ offs,
                            int* __restrict__ fill, int* __restrict__ esrc) {
    const int i = blockIdx.x * blockDim.x + threadIdx.x;
    if (i >= NE) return;
    const int src = ei[i], dst = ei[NE + i];
    const int pos = offs[dst] + atomicAdd(&fill[dst], 1);
    esrc[pos] = src;
}

// ------- GEMM (K=128): DMA dbuf staging, RPT-row reg blocking, KC=16 ---------
// 128-thread blocks. Lane g owns 4 float4 col chunks at stride CS=BN/4
// (W reads conflict-free: same-g lanes broadcast, groups hit distinct banks).
// RPT=4 rows/lane halves W LDS-read traffic vs RPT=2 (round-12: LDS-read bound).
// X stored source-swizzled: slot d holds X[row=d>>2][f4col=(d&3)^((row>>1)&3)];
// read with same XOR -> worst 2-way (free, m136). No reg staging (round-5 spill).
template<int BN, int RPT, bool WRITE_Y, bool WRITE_H16>
__global__ __launch_bounds__(128, 4) void gemm_k128(const float* __restrict__ X,
                                                    const float* __restrict__ Wm,
                                                    const float* __restrict__ attS,
                                                    const float* __restrict__ attD,
                                                    float* __restrict__ Y,
                                                    uint32* __restrict__ H16,
                                                    float* __restrict__ asrcO,
                                                    float* __restrict__ adstO, int M) {
    constexpr int GROUPS = BN / 16;      // 8 (BN=128) or 4 (BN=64)
    constexpr int NR = 128 / GROUPS;     // 16 or 32
    constexpr int BM = NR * RPT;         // 64 or 128 rows/block
    constexpr int KC = 16;               // k-chunk
    constexpr int CS = BN / 4;
    constexpr int NXC = BM * KC / 512;   // X 16B-DMAs per thread per kk
    constexpr int NWC = KC * BN / 512;   // W 16B-DMAs per thread per kk
    __shared__ __align__(16) float Xs[2][BM * KC];
    __shared__ __align__(16) float Ws[2][KC * BN];

    const int tid = threadIdx.x;
    const int r  = tid / GROUPS;         // 0..NR-1 (owns rows r + NR*p)
    const int g  = tid % GROUPS;
    const int g4 = g * 4;
    const int wv = tid >> 6;             // wave id (uniform per wave)
    const int rowBase = blockIdx.x * BM;
    const int swz = (r >> 1) & 3;        // same for r+NR*p (NR%8==0)

    auto stage = [&](int kk, int b) {
        float* XsB = &Xs[b][0];
        float* WsB = &Ws[b][0];
        #pragma unroll
        for (int t = 0; t < NXC; ++t) {
            const int d  = t * 128 + tid;              // slot id
            const int xr = d >> 2;
            const int kc = (d & 3) ^ ((xr >> 1) & 3);  // source-side swizzle
            int xrow = rowBase + xr;
            if (xrow >= M) xrow = M - 1;               // clamp (no OOB DMA)
            gload16(X + xrow * 128 + kk * KC + kc * 4,
                    XsB + (t * 128 + wv * 64) * 4);    // uniform base; +lane*16 auto
        }
        #pragma unroll
        for (int t = 0; t < NWC; ++t) {
            const int d = t * 128 + tid;
            gload16(Wm + kk * KC * BN + d * 4,
                    WsB + (t * 128 + wv * 64) * 4);
        }
    };

    float4 acc[RPT][4];
    #pragma unroll
    for (int p = 0; p < RPT; ++p)
        #pragma unroll
        for (int j = 0; j < 4; ++j) acc[p][j] = {0, 0, 0, 0};

    stage(0, 0);
    __syncthreads();                                   // compiler drains vmcnt
    for (int kk = 0; kk < 8; ++kk) {
        const int cur = kk & 1;
        if (kk < 7) stage(kk + 1, cur ^ 1);
        const float* XsC = &Xs[cur][0];
        const float* WsC = &Ws[cur][0];
        #pragma unroll
        for (int kc = 0; kc < 4; ++kc) {
            float4 xq[RPT];
            #pragma unroll
            for (int p = 0; p < RPT; ++p)
                xq[p] = *reinterpret_cast<const float4*>(
                    XsC + ((r + NR * p) * 4 + (kc ^ swz)) * 4);
            #pragma unroll
            for (int e = 0; e < 4; ++e) {
                const int k = kc * 4 + e;
                const float* wp = WsC + k * BN + g4;
                const float4 w0 = *reinterpret_cast<const float4*>(wp);
                const float4 w1 = *reinterpret_cast<const float4*>(wp + CS);
                const float4 w2 = *reinterpret_cast<const float4*>(wp + 2 * CS);
                const float4 w3 = *reinterpret_cast<const float4*>(wp + 3 * CS);
                #pragma unroll
                for (int p = 0; p < RPT; ++p) {
                    const float xv = (e == 0) ? xq[p].x : (e == 1) ? xq[p].y
                                   : (e == 2) ? xq[p].z : xq[p].w;
                    acc[p][0].x += xv * w0.x; acc[p][0].y += xv * w0.y;
                    acc[p][0].z += xv * w0.z; acc[p][0].w += xv * w0.w;
                    acc[p][1].x += xv * w1.x; acc[p][1].y += xv * w1.y;
                    acc[p][1].z += xv * w1.z; acc[p][1].w += xv * w1.w;
                    acc[p][2].x += xv * w2.x; acc[p][2].y += xv * w2.y;
                    acc[p][2].z += xv * w2.z; acc[p][2].w += xv * w2.w;
                    acc[p][3].x += xv * w3.x; acc[p][3].y += xv * w3.y;
                    acc[p][3].z += xv * w3.z; acc[p][3].w += xv * w3.w;
                }
            }
        }
        __syncthreads();
    }

    const float4* avs = reinterpret_cast<const float4*>(attS);
    const float4* avd = reinterpret_cast<const float4*>(attD);
    #pragma unroll
    for (int p = 0; p < RPT; ++p) {
        const float4* a = acc[p];
        const int grow = rowBase + r + NR * p;
        if (grow < M) {
            if (WRITE_Y) {
                float* yrow = &Y[grow * BN + g4];
                *reinterpret_cast<float4*>(yrow)          = a[0];
                *reinterpret_cast<float4*>(yrow + CS)     = a[1];
                *reinterpret_cast<float4*>(yrow + 2 * CS) = a[2];
                *reinterpret_cast<float4*>(yrow + 3 * CS) = a[3];
            }
            if (WRITE_H16) {
                uint32* hrow = &H16[grow * (BN / 2)];
                #pragma unroll
                for (int j = 0; j < 4; ++j) {
                    uint2 u;
                    u.x = packbf2(a[j].x, a[j].y);
                    u.y = packbf2(a[j].z, a[j].w);
                    *reinterpret_cast<uint2*>(&hrow[g * 2 + j * (CS / 2)]) = u;
                }
            }
        }
        float ps0 = dot4(a[0], avs[g])              + dot4(a[1], avs[g + GROUPS]);
        float ps1 = dot4(a[2], avs[g + 2 * GROUPS]) + dot4(a[3], avs[g + 3 * GROUPS]);
        float pd0 = dot4(a[0], avd[g])              + dot4(a[1], avd[g + GROUPS]);
        float pd1 = dot4(a[2], avd[g + 2 * GROUPS]) + dot4(a[3], avd[g + 3 * GROUPS]);
        #pragma unroll
        for (int d = 1; d < GROUPS; d <<= 1) {
            ps0 += __shfl_xor(ps0, d);
            ps1 += __shfl_xor(ps1, d);
            pd0 += __shfl_xor(pd0, d);
            pd1 += __shfl_xor(pd1, d);
        }
        if (g == 0 && grow < M) {
            asrcO[grow * 2]     = ps0;
            asrcO[grow * 2 + 1] = ps1;
            adstO[grow * 2]     = pd0;
            adstO[grow * 2 + 1] = pd1;
        }
    }
}

// ---------------- fused per-dst exact softmax + aggregation (layer 1) ---------
// one wave per dst; lane owns chans {2*lane, 2*lane+1}; head h = lane>>5.
// phase1: wave-parallel max; phase2: UNROLL-4 batched gathers (4 in flight).
// Shuffle BOTH pe0,pe1 then select by h AFTER (round-11 source-lane-eval bug).
__global__ __launch_bounds__(256) void gat_dst1(const int* __restrict__ esrc,
                                                const int* __restrict__ offs,
                                                const uint32* __restrict__ H16,
                                                const float* __restrict__ asrc,
                                                const float* __restrict__ adst,
                                                const float* __restrict__ bias1,
                                                float* __restrict__ out) {
    const int wid  = (blockIdx.x * blockDim.x + threadIdx.x) >> 6;
    const int lane = threadIdx.x & 63;
    if (wid >= NN) return;
    const int dst = wid;
    const int beg = offs[dst];
    const int end = (dst == NN - 1) ? NE : offs[dst + 1];
    const int deg = end - beg;
    const float2 ad = *reinterpret_cast<const float2*>(&adst[dst * 2]);

    int   s0  = 0;
    float pe0 = -INFINITY, pe1 = -INFINITY;
    float m0  = -INFINITY, m1  = -INFINITY;
    for (int j = lane; j < deg; j += 64) {
        const int s = esrc[beg + j];
        const float2 a = *reinterpret_cast<const float2*>(&asrc[s * 2]);
        const float f0 = lrelu(a.x + ad.x);
        const float f1 = lrelu(a.y + ad.y);
        if (j == lane) { s0 = s; pe0 = f0; pe1 = f1; }
        m0 = fmaxf(m0, f0); m1 = fmaxf(m1, f1);
    }
    const float2 aself = *reinterpret_cast<const float2*>(&asrc[dst * 2]);
    const float es0 = lrelu(aself.x + ad.x);
    const float es1 = lrelu(aself.y + ad.y);
    m0 = fmaxf(m0, es0); m1 = fmaxf(m1, es1);
    #pragma unroll
    for (int d = 1; d < 64; d <<= 1) {
        m0 = fmaxf(m0, __shfl_xor(m0, d));
        m1 = fmaxf(m1, __shfl_xor(m1, d));
    }
    const int h = lane >> 5;
    const float m = h ? m1 : m0;

    float l;
    float2 acc;
    {
        const float px = __expf((h ? es1 : es0) - m);
        l = px;
        const uint32 u = H16[dst * 64 + lane];
        acc.x = px * __uint_as_float(u << 16);
        acc.y = px * __uint_as_float(u & 0xffff0000u);
    }
    const int jmax = deg < 64 ? deg : 64;
    int j = 0;
    for (; j + 3 < jmax; j += 4) {
        const int sa = __shfl(s0, j),     sb = __shfl(s0, j + 1);
        const int sc = __shfl(s0, j + 2), sd = __shfl(s0, j + 3);
        const float ta0 = __shfl(pe0, j),     ta1 = __shfl(pe1, j);
        const float tb0 = __shfl(pe0, j + 1), tb1 = __shfl(pe1, j + 1);
        const float tc0 = __shfl(pe0, j + 2), tc1 = __shfl(pe1, j + 2);
        const float td0 = __shfl(pe0, j + 3), td1 = __shfl(pe1, j + 3);
        const uint32 ua = H16[sa * 64 + lane];        // 4 gathers in flight
        const uint32 ub = H16[sb * 64 + lane];
        const uint32 uc = H16[sc * 64 + lane];
        const uint32 ud = H16[sd * 64 + lane];
        const float pa = __expf((h ? ta1 : ta0) - m);
        const float pb = __expf((h ? tb1 : tb0) - m);
        const float pc = __expf((h ? tc1 : tc0) - m);
        const float pd = __expf((h ? td1 : td0) - m);
        l += (pa + pb) + (pc + pd);
        acc.x += pa * __uint_as_float(ua << 16) + pb * __uint_as_float(ub << 16)
               + pc * __uint_as_float(uc << 16) + pd * __uint_as_float(ud << 16);
        acc.y += pa * __uint_as_float(ua & 0xffff0000u) + pb * __uint_as_float(ub & 0xffff0000u)
               + pc * __uint_as_float(uc & 0xffff0000u) + pd * __uint_as_float(ud & 0xffff0000u);
    }
    for (; j < jmax; ++j) {
        const int s = __shfl(s0, j);
        const float t0 = __shfl(pe0, j), t1 = __shfl(pe1, j);
        const float p = __expf((h ? t1 : t0) - m);
        const uint32 u = H16[s * 64 + lane];
        l += p;
        acc.x += p * __uint_as_float(u << 16);
        acc.y += p * __uint_as_float(u & 0xffff0000u);
    }
    for (int j2 = 64; j2 < deg; ++j2) {       // astronomically rare (deg>64)
        const int s = esrc[beg + j2];
        const float2 a = *reinterpret_cast<const float2*>(&asrc[s * 2]);
        const float p = __expf(lrelu((h ? a.y : a.x) + (h ? ad.y : ad.x)) - m);
        const uint32 u = H16[s * 64 + lane];
        l += p;
        acc.x += p * __uint_as_float(u << 16);
        acc.y += p * __uint_as_float(u & 0xffff0000u);
    }
    const float inv = 1.0f / (l + 1e-16f);
    const float2 bb = *reinterpret_cast<const float2*>(&bias1[lane * 2]);
    float2 res;
    res.x = fmaxf(acc.x * inv + bb.x, 0.0f);   // fused relu(out1 + b1)
    res.y = fmaxf(acc.y * inv + bb.y, 0.0f);
    *reinterpret_cast<float2*>(&out[dst * 128 + lane * 2]) = res;
}

// ------- layer 2: same structure + head-mean; bf16 H16b [N,32 u32] ------------
// lane owns chan `lane` (head lane>>5). bf16 gather halves traffic; error is
// further halved by the 0.5 head-mean at the output.
__global__ __launch_bounds__(256) void gat_dst2(const int* __restrict__ esrc,
                                                const int* __restrict__ offs,
                                                const uint32* __restrict__ H16b,
                                                const float* __restrict__ asrc,
                                                const float* __restrict__ adst,
                                                const float* __restrict__ bias,
                                                float* __restrict__ out) {
    const int wid  = (blockIdx.x * blockDim.x + threadIdx.x) >> 6;
    const int lane = threadIdx.x & 63;
    if (wid >= NN) return;
    const int dst = wid;
    const int beg = offs[dst];
    const int end = (dst == NN - 1) ? NE : offs[dst + 1];
    const int deg = end - beg;
    const int odd = lane & 1;
    const float2 ad = *reinterpret_cast<const float2*>(&adst[dst * 2]);

    int   s0  = 0;
    float pe0 = -INFINITY, pe1 = -INFINITY;
    float m0  = -INFINITY, m1  = -INFINITY;
    for (int j = lane; j < deg; j += 64) {
        const int s = esrc[beg + j];
        const float2 a = *reinterpret_cast<const float2*>(&asrc[s * 2]);
        const float f0 = lrelu(a.x + ad.x);
        const float f1 = lrelu(a.y + ad.y);
        if (j == lane) { s0 = s; pe0 = f0; pe1 = f1; }
        m0 = fmaxf(m0, f0); m1 = fmaxf(m1, f1);
    }
    const float2 aself = *reinterpret_cast<const float2*>(&asrc[dst * 2]);
    const float es0 = lrelu(aself.x + ad.x);
    const float es1 = lrelu(aself.y + ad.y);
    m0 = fmaxf(m0, es0); m1 = fmaxf(m1, es1);
    #pragma unroll
    for (int d = 1; d < 64; d <<= 1) {
        m0 = fmaxf(m0, __shfl_xor(m0, d));
        m1 = fmaxf(m1, __shfl_xor(m1, d));
    }
    const int h = lane >> 5;
    const float m = h ? m1 : m0;

    float l, acc;
    {
        const float px = __expf((h ? es1 : es0) - m);
        l = px;
        acc = px * bfsel(H16b[dst * 32 + (lane >> 1)], odd);
    }
    const int jmax = deg < 64 ? deg : 64;
    int j = 0;
    for (; j + 3 < jmax; j += 4) {
        const int sa = __shfl(s0, j),     sb = __shfl(s0, j + 1);
        const int sc = __shfl(s0, j + 2), sd = __shfl(s0, j + 3);
        const float ta0 = __shfl(pe0, j),     ta1 = __shfl(pe1, j);
        const float tb0 = __shfl(pe0, j + 1), tb1 = __shfl(pe1, j + 1);
        const float tc0 = __shfl(pe0, j + 2), tc1 = __shfl(pe1, j + 2);
        const float td0 = __shfl(pe0, j + 3), td1 = __shfl(pe1, j + 3);
        const uint32 ua = H16b[sa * 32 + (lane >> 1)];   // 4 gathers in flight
        const uint32 ub = H16b[sb * 32 + (lane >> 1)];
        const uint32 uc = H16b[sc * 32 + (lane >> 1)];
        const uint32 ud = H16b[sd * 32 + (lane >> 1)];
        const float pa = __expf((h ? ta1 : ta0) - m);
        const float pb = __expf((h ? tb1 : tb0) - m);
        const float pc = __expf((h ? tc1 : tc0) - m);
        const float pd = __expf((h ? td1 : td0) - m);
        l += (pa + pb) + (pc + pd);
        acc += pa * bfsel(ua, odd) + pb * bfsel(ub, odd)
             + pc * bfsel(uc, odd) + pd * bfsel(ud, odd);
    }
    for (; j < jmax; ++j) {
        const int s = __shfl(s0, j);
        const float t0 = __shfl(pe0, j), t1 = __shfl(pe1, j);
        const float p = __expf((h ? t1 : t0) - m);
        l += p;
        acc += p * bfsel(H16b[s * 32 + (lane >> 1)], odd);
    }
    for (int j2 = 64; j2 < deg; ++j2) {       // astronomically rare
        const int s = esrc[beg + j2];
        const float2 a = *reinterpret_cast<const float2*>(&asrc[s * 2]);
        const float p = __expf(lrelu((h ? a.y : a.x) + (h ? ad.y : ad.x)) - m);
        l += p;
        acc += p * bfsel(H16b[s * 32 + (lane >> 1)], odd);
    }
    float r = acc / (l + 1e-16f);
    r += __shfl_xor(r, 32);                   // combine heads
    if (lane < 32) out[dst * 32 + lane] = 0.5f * r + bias[lane];
}

// ---------------- launch ----------------
extern "C" void kernel_launch(void* const* d_in, const int* in_sizes, int n_in,
                              void* d_out, int out_size, void* d_ws, size_t ws_size,
                              hipStream_t stream) {
    const float* x   = (const float*)d_in[0];
    const int*   ei  = (const int*)d_in[1];
    const float* W1  = (const float*)d_in[2];
    const float* as1 = (const float*)d_in[3];
    const float* ad1 = (const float*)d_in[4];
    const float* b1  = (const float*)d_in[5];
    const float* W2  = (const float*)d_in[6];
    const float* as2 = (const float*)d_in[7];
    const float* ad2 = (const float*)d_in[8];
    const float* b2  = (const float*)d_in[9];
    float* out = (float*)d_out;

    // Workspace: ~12.6 M floats = 50.2 MB (< proven 56.6 MB).
    float* ws = (float*)d_ws;
    size_t off = 0;
    float* out1  = ws + off; off += (size_t)NN * FIN;   // [N,128] relu(out1+b1)
    float* asrc1 = ws + off; off += (size_t)NN * NH;
    float* adst1 = ws + off; off += (size_t)NN * NH;
    float* asrc2 = ws + off; off += (size_t)NN * NH;
    float* adst2 = ws + off; off += (size_t)NN * NH;
    uint32* h16  = (uint32*)(ws + off); off += (size_t)NN * 64;  // bf16 [N,128]
    uint32* h16b = (uint32*)(ws + off); off += (size_t)NN * 32;  // bf16 [N,64]
    int* ibase = (int*)(ws + off);
    int* deg   = ibase;                 // [NN]  \ adjacent: one zero_ints
    int* fill  = ibase + NN;            // [NN]  /
    int* offs  = ibase + 2 * NN;        // [NN]
    int* bsum  = ibase + 3 * NN;        // [256]
    int* esrc  = ibase + 3 * NN + 256;  // [NE]

    const int B = 256;
    constexpr int NB_SCAN = (NN + 255) / 256;   // 196

    // ---- CSR build (shared by both layers) ----
    zero_ints<<<128, B, 0, stream>>>(deg, 2 * NN);   // deg + fill
    hist_dst<<<(NE + B - 1) / B, B, 0, stream>>>(ei, deg);
    scan_blocks<<<NB_SCAN, 256, 0, stream>>>(deg, offs, bsum);
    scan_bsums<<<1, 256, 0, stream>>>(bsum, NB_SCAN);
    scan_add<<<NB_SCAN, 256, 0, stream>>>(offs, bsum);
    csr_scatter<<<(NE + B - 1) / B, B, 0, stream>>>(ei, offs, fill, esrc);

    // ---- layer 1 ----  (gemm writes bf16 H only; BM=64 -> 782 blocks, 128 thr)
    gemm_k128<128, 4, false, true><<<(NN + 63) / 64, 128, 0, stream>>>(
        x, W1, as1, ad1, nullptr, h16, asrc1, adst1, NN);
    gat_dst1<<<(NN * 64 + B - 1) / B, B, 0, stream>>>(
        esrc, offs, h16, asrc1, adst1, b1, out1);

    // ---- layer 2 ----  (gemm writes bf16 H16b; BM=128 -> 391 blocks, 128 thr)
    gemm_k128<64, 4, false, true><<<(NN + 127) / 128, 128, 0, stream>>>(
        out1, W2, as2, ad2, nullptr, h16b, asrc2, adst2, NN);
    gat_dst2<<<(NN * 64 + B - 1) / B, B, 0, stream>>>(
        esrc, offs, h16b, asrc2, adst2, b2, out);
}